// Round 17
// baseline (317.087 us; speedup 1.0000x reference)
//
#include <hip/hip_runtime.h>
#include <cmath>

// Decoder_spirals R16: R15 + fc merged into cvt_all (guest<<host grid fusion --
// the safe direction of R14's failed experiment). fc blocks [0,93) run first and
// hide under the BW-bound cvt loop (~40us). 7 dispatches. GEMMs identical to R15.

#define NB 16

typedef __attribute__((ext_vector_type(8))) short bf16x8;
typedef __attribute__((ext_vector_type(4))) float f32x4;

__device__ __forceinline__ unsigned short f2bf(float x) {
    union { float f; unsigned u; } v; v.f = x;
    unsigned r = v.u + 0x7FFFu + ((v.u >> 16) & 1u);
    return (unsigned short)(r >> 16);
}
__device__ __forceinline__ void gload16(const void* src, void* dst) {
    __builtin_amdgcn_global_load_lds(
        (const __attribute__((address_space(1))) unsigned int*)src,
        (__attribute__((address_space(3))) unsigned int*)dst, 16, 0, 0);
}

// ------------- converter + FC (fused; fc blocks [0,93), cvt blocks [93,...)) -------------
__global__ __launch_bounds__(256) void cvt_fc(
    const float* __restrict__ z, const float* __restrict__ Wfc,
    const float* __restrict__ bfc, unsigned short* __restrict__ x3T,
    const float* __restrict__ U0, const float* __restrict__ U1,
    const float* __restrict__ U2, unsigned* __restrict__ Ub0,
    unsigned* __restrict__ Ub1, unsigned* __restrict__ Ub2,
    const float* __restrict__ W0, const float* __restrict__ W1,
    const float* __restrict__ W2, const int* __restrict__ S0,
    const int* __restrict__ S1, const int* __restrict__ S2,
    unsigned short* __restrict__ W0T, unsigned short* __restrict__ W1T,
    unsigned short* __restrict__ W2T, int* __restrict__ S0T,
    int* __restrict__ S1T, int* __restrict__ S2T) {
    const int t = threadIdx.x;
    if (blockIdx.x < 93) {
        // ---- FC: z(16,128)@Wfc + bfc -> x3T[b*128+f][192] bf16 (+pad zero) ----
        const int N = 185 * 128;
        __shared__ float zs[NB * 128];
        for (int i = t; i < NB * 128; i += 256) zs[i] = z[i];
        __syncthreads();
        int n = blockIdx.x * 256 + t;
        if (n >= N) return;
        float acc[NB];
#pragma unroll
        for (int b = 0; b < NB; ++b) acc[b] = 0.f;
        for (int k = 0; k < 128; ++k) {
            float w = Wfc[k * N + n];
#pragma unroll
            for (int b = 0; b < NB; ++b) acc[b] = fmaf(zs[b * 128 + k], w, acc[b]);
        }
        float bv = bfc[n];
        int f = n & 127, v = n >> 7;
#pragma unroll
        for (int b = 0; b < NB; ++b)
            x3T[(size_t)(b * 128 + f) * 192 + v] = f2bf(acc[b] + bv);
        if (n < 7 * 128) {
            int vp = 185 + (n >> 7);
#pragma unroll
            for (int b = 0; b < NB; ++b)
                x3T[(size_t)(b * 128 + f) * 192 + vp] = 0;
        }
        return;
    }
    // ---- converters (grid-stride over the cvt sub-grid) ----
    const unsigned nth = (gridDim.x - 93u) * 256u;
    const unsigned tid = (blockIdx.x - 93u) * 256u + t;
    // U0 pairs: [11904][1488]
    for (unsigned p = tid; p < 11904u * 1488u; p += nth) {
        unsigned row = p / 1488u;
        unsigned k = (p - row * 1488u) * 2u;
        float v0 = 0.f, v1 = 0.f;
        if (row < 11794u) {
            const float* s = U0 + (size_t)row * 2949u + k;
            if (k < 2949u) v0 = s[0];
            if (k + 1u < 2949u) v1 = s[1];
        }
        Ub0[p] = (unsigned)f2bf(v0) | ((unsigned)f2bf(v1) << 16);
    }
    // U1 pairs: [3072][384]
    for (unsigned p = tid; p < 3072u * 384u; p += nth) {
        unsigned row = p / 384u;
        unsigned k = (p - row * 384u) * 2u;
        float v0 = 0.f, v1 = 0.f;
        if (row < 2949u) {
            const float* s = U1 + (size_t)row * 738u + k;
            if (k < 738u) v0 = s[0];
            if (k + 1u < 738u) v1 = s[1];
        }
        Ub1[p] = (unsigned)f2bf(v0) | ((unsigned)f2bf(v1) << 16);
    }
    // U2 pairs: [768][96]
    for (unsigned p = tid; p < 768u * 96u; p += nth) {
        unsigned row = p / 96u;
        unsigned k = (p - row * 96u) * 2u;
        float v0 = 0.f, v1 = 0.f;
        if (row < 738u) {
            const float* s = U2 + (size_t)row * 185u + k;
            if (k < 185u) v0 = s[0];
            if (k + 1u < 185u) v1 = s[1];
        }
        Ub2[p] = (unsigned)f2bf(v0) | ((unsigned)f2bf(v1) << 16);
    }
    // weight / spiral transposes
    const unsigned N0 = 128 * 1536, N1 = 64 * 1792, N2 = 16 * 1288;
    const unsigned N3 = 20 * 11794, N4 = 14 * 2949, N5 = 12 * 738;
    const unsigned TOT = N0 + N1 + N2 + N3 + N4 + N5;
    for (unsigned id0 = tid; id0 < TOT; id0 += nth) {
        unsigned id = id0;
        if (id < N0) {
            unsigned n = id / 1536u, k = id - n * 1536u;
            W0T[id] = f2bf(W0[(size_t)k * 128 + n]);
        } else if ((id -= N0) < N1) {
            unsigned n = id / 1792u, k = id - n * 1792u;
            W1T[id] = f2bf(W1[(size_t)k * 64 + n]);
        } else if ((id -= N1) < N2) {
            unsigned n = id / 1288u, k = id - n * 1288u;
            float v = (n < 3u && k < 1280u) ? W2[(size_t)k * 3 + n] : 0.f;
            W2T[id] = f2bf(v);
        } else if ((id -= N2) < N3) {
            unsigned k = id / 11794u, v = id - k * 11794u;
            S0T[id] = S0[(size_t)v * 20 + k];
        } else if ((id -= N3) < N4) {
            unsigned k = id / 2949u, v = id - k * 2949u;
            S1T[id] = S1[(size_t)v * 14 + k];
        } else if ((id -= N4) < N5) {
            unsigned k = id / 738u, v = id - k * 738u;
            S2T[id] = S2[(size_t)v * 12 + k];
        }
    }
}

// ------------- Upsample: BM=BN=128, wave=64x64; 3-buf, 2-deep, vmcnt(4) -------------
template<int FSH, int VP>
__global__ __launch_bounds__(256) void ups_mfma(
    const unsigned short* __restrict__ Ub, const unsigned short* __restrict__ xT,
    unsigned short* __restrict__ out,
    int WpA, int WpB, int nsteps, int gxsh, int q) {
    const int F = 1 << FSH;
    __shared__ __align__(16) unsigned short As[3][128 * 32];
    __shared__ __align__(16) unsigned short Bs[3][128 * 32];
    const int t = threadIdx.x;
    const int wv = t >> 6, lane = t & 63;
    const int lr = lane & 15;

    const int flat = blockIdx.x;
    const int wg = (flat & 7) * q + (flat >> 3);
    const int m0 = (wg >> gxsh) * 128;
    const int n0 = (wg & ((1 << gxsh) - 1)) * 128;

    const int srow = lane >> 2;
    const int schunk = (((lane & 3) - ((lane >> 3) & 3)) & 3) * 8;
    const int ii0 = wv * 2, ii1 = wv * 2 + 1;
    const unsigned short* asrc0 = Ub + (size_t)(m0 + ii0 * 16 + srow) * WpA + schunk;
    const unsigned short* asrc1 = Ub + (size_t)(m0 + ii1 * 16 + srow) * WpA + schunk;
    const unsigned short* bsrc0 = xT + (size_t)(n0 + ii0 * 16 + srow) * WpB + schunk;
    const unsigned short* bsrc1 = xT + (size_t)(n0 + ii1 * 16 + srow) * WpB + schunk;

    const int fslot = (((lane >> 4) + (lr >> 1)) & 3) * 8;
    const int wrow = (wv >> 1) * 64;
    const int wcol = (wv & 1) * 64;
    const int u0 = wv * 1024;

    f32x4 acc[4][4];
#pragma unroll
    for (int i = 0; i < 4; ++i)
#pragma unroll
        for (int j = 0; j < 4; ++j) acc[i][j] = {0.f, 0.f, 0.f, 0.f};

#define UPS_STAGE(off_, B_)                                             \
    {                                                                   \
        gload16(asrc0 + (off_), &As[B_][u0]);                           \
        gload16(bsrc0 + (off_), &Bs[B_][u0]);                           \
        gload16(asrc1 + (off_), &As[B_][u0 + 512]);                     \
        gload16(bsrc1 + (off_), &Bs[B_][u0 + 512]);                     \
    }
#define UPS_COMPUTE(B_)                                                 \
    {                                                                   \
        bf16x8 af[4], bg[4];                                            \
        _Pragma("unroll")                                               \
        for (int mt = 0; mt < 4; ++mt)                                  \
            af[mt] = *(const bf16x8*)&As[B_][(wrow + mt * 16 + lr) * 32 + fslot]; \
        _Pragma("unroll")                                               \
        for (int nt = 0; nt < 4; ++nt)                                  \
            bg[nt] = *(const bf16x8*)&Bs[B_][(wcol + nt * 16 + lr) * 32 + fslot]; \
        _Pragma("unroll")                                               \
        for (int mt = 0; mt < 4; ++mt)                                  \
            _Pragma("unroll")                                           \
            for (int nt = 0; nt < 4; ++nt)                              \
                acc[mt][nt] = __builtin_amdgcn_mfma_f32_16x16x32_bf16(  \
                    af[mt], bg[nt], acc[mt][nt], 0, 0, 0);              \
    }
#define UPS_WAIT4 asm volatile("s_waitcnt vmcnt(4)" ::: "memory"); __builtin_amdgcn_s_barrier();
#define UPS_WAIT0 asm volatile("s_waitcnt vmcnt(0)" ::: "memory"); __builtin_amdgcn_s_barrier();

    UPS_STAGE(0, 0);
    UPS_STAGE(32, 1);
    UPS_WAIT4;

    const int m = nsteps / 3;
    for (int it = 0; it < m - 1; ++it) {
        UPS_STAGE(64, 2);  UPS_COMPUTE(0); UPS_WAIT4;
        UPS_STAGE(96, 0);  UPS_COMPUTE(1); UPS_WAIT4;
        UPS_STAGE(128, 1); UPS_COMPUTE(2); UPS_WAIT4;
        asrc0 += 96; asrc1 += 96; bsrc0 += 96; bsrc1 += 96;
    }
    UPS_STAGE(64, 2);
    UPS_COMPUTE(0); UPS_WAIT4;
    UPS_COMPUTE(1); UPS_WAIT0;
    UPS_COMPUTE(2);
#undef UPS_STAGE
#undef UPS_COMPUTE
#undef UPS_WAIT4
#undef UPS_WAIT0

#pragma unroll
    for (int mt = 0; mt < 4; ++mt) {
        const int vb = m0 + wrow + mt * 16 + (lane >> 4) * 4;
#pragma unroll
        for (int nt = 0; nt < 4; ++nt) {
            const int col = n0 + wcol + nt * 16 + lr;
            const int b = col >> FSH, f = col & (F - 1);
            unsigned short* op = out + (size_t)b * VP * F + f;
#pragma unroll
            for (int j = 0; j < 4; ++j)
                op[(size_t)(vb + j) * F] = f2bf(acc[mt][nt][j]);
        }
    }
}

// ------- SpiralConv: barrierless 1-wave 32-row tiles, full unroll, Fin=128 -------
template<int VP, int NSTEPS, int KSP>
__global__ __launch_bounds__(64) void conv_mfma(
    const unsigned short* __restrict__ xu, const int* __restrict__ ST,
    const unsigned short* __restrict__ WT, const float* __restrict__ bias,
    unsigned short* __restrict__ outT,
    int VT, int Kdim, int Fout) {
    __shared__ __align__(16) unsigned short As[2][32 * 32];
    __shared__ __align__(16) unsigned short Bs[3][64 * 32];
    const int lane = threadIdx.x;
    const int lr = lane & 15;
    const int m0 = blockIdx.x * 32;
    const int n0 = blockIdx.y * 64;
    const int b = m0 / VP;
    const int v0 = m0 - b * VP;
    const unsigned short* xb = xu + (((size_t)b * VP) << 7);

    const int arow = lane >> 1;
    const int h = lane & 1;
    const int vg = (v0 + arow < VT) ? (v0 + arow) : (VT - 1);
    const int schunk = (((lane & 3) - ((lane >> 3) & 3)) & 3) * 8;
    const int fslot = (((lane >> 4) + (lr >> 1)) & 3) * 8;
    const int sw0 = arow * 32 + (((2 * h + 0 + ((lane >> 2) & 3)) & 3) * 8);
    const int sw1 = arow * 32 + (((2 * h + 1 + ((lane >> 2) & 3)) & 3) * 8);

    int idx[KSP];
#pragma unroll
    for (int k = 0; k < KSP; ++k) idx[k] = ST[(size_t)k * VT + vg];

    f32x4 acc[2][4];
#pragma unroll
    for (int i = 0; i < 2; ++i)
#pragma unroll
        for (int j = 0; j < 4; ++j) acc[i][j] = {0.f, 0.f, 0.f, 0.f};

    bf16x8 gA[2][2];

#define CC(AB_, BB_)                                                    \
    {                                                                   \
        bf16x8 af[2], bg[4];                                            \
        _Pragma("unroll")                                               \
        for (int mt = 0; mt < 2; ++mt)                                  \
            af[mt] = *(const bf16x8*)&As[AB_][(mt * 16 + lr) * 32 + fslot]; \
        _Pragma("unroll")                                               \
        for (int nt = 0; nt < 4; ++nt)                                  \
            bg[nt] = *(const bf16x8*)&Bs[BB_][(nt * 16 + lr) * 32 + fslot]; \
        _Pragma("unroll")                                               \
        for (int mt = 0; mt < 2; ++mt)                                  \
            _Pragma("unroll")                                           \
            for (int nt = 0; nt < 4; ++nt)                              \
                acc[mt][nt] = __builtin_amdgcn_mfma_f32_16x16x32_bf16(  \
                    af[mt], bg[nt], acc[mt][nt], 0, 0, 0);              \
    }

    {
        const unsigned short* p = xb + (((size_t)idx[0]) << 7) + h * 16;
        gA[0][0] = *(const bf16x8*)(p);
        gA[0][1] = *(const bf16x8*)(p + 8);
#pragma unroll
        for (int i = 0; i < 4; ++i) {
            const int n = n0 + i * 16 + (lane >> 2);
            gload16(WT + (size_t)n * Kdim + schunk, &Bs[0][i * 512]);
        }
#pragma unroll
        for (int i = 0; i < 4; ++i) {
            const int n = n0 + i * 16 + (lane >> 2);
            gload16(WT + (size_t)n * Kdim + 32 + schunk, &Bs[1][i * 512]);
        }
        *(bf16x8*)&As[0][sw0] = gA[0][0];
        *(bf16x8*)&As[0][sw1] = gA[0][1];
        asm volatile("s_waitcnt vmcnt(4)" ::: "memory");
    }

#pragma unroll
    for (int ts = 0; ts < NSTEPS - 2; ++ts) {
        const int tn1 = ts + 1, tn2 = ts + 2;
        {
            const unsigned short* p =
                xb + (((size_t)idx[tn1 >> 2]) << 7) + (tn1 & 3) * 32 + h * 16;
            gA[tn1 & 1][0] = *(const bf16x8*)(p);
            gA[tn1 & 1][1] = *(const bf16x8*)(p + 8);
        }
        {
            const int k0 = tn2 * 32;
#pragma unroll
            for (int i = 0; i < 4; ++i) {
                const int n = n0 + i * 16 + (lane >> 2);
                gload16(WT + (size_t)n * Kdim + k0 + schunk, &Bs[tn2 % 3][i * 512]);
            }
        }
        CC(ts & 1, ts % 3);
        asm volatile("s_waitcnt vmcnt(4)" ::: "memory");
        *(bf16x8*)&As[tn1 & 1][sw0] = gA[tn1 & 1][0];
        *(bf16x8*)&As[tn1 & 1][sw1] = gA[tn1 & 1][1];
    }
    {
        const int tn1 = NSTEPS - 1;
        const unsigned short* p =
            xb + (((size_t)idx[tn1 >> 2]) << 7) + (tn1 & 3) * 32 + h * 16;
        gA[tn1 & 1][0] = *(const bf16x8*)(p);
        gA[tn1 & 1][1] = *(const bf16x8*)(p + 8);
        CC((NSTEPS - 2) & 1, (NSTEPS - 2) % 3);
        asm volatile("s_waitcnt vmcnt(0)" ::: "memory");
        *(bf16x8*)&As[tn1 & 1][sw0] = gA[tn1 & 1][0];
        *(bf16x8*)&As[tn1 & 1][sw1] = gA[tn1 & 1][1];
    }
    CC((NSTEPS - 1) & 1, (NSTEPS - 1) % 3);
#undef CC

#pragma unroll
    for (int nt = 0; nt < 4; ++nt) {
        const int n = n0 + nt * 16 + lr;
        const float bv = bias[n];
        unsigned short* op = outT + (size_t)(b * Fout + n) * VP;
#pragma unroll
        for (int mt = 0; mt < 2; ++mt) {
            const int v = v0 + mt * 16 + (lane >> 4) * 4;
            ushort4 stv;
#pragma unroll
            for (int j = 0; j < 4; ++j) {
                float val = acc[mt][nt][j] + bv;
                val = val > 0.f ? val : expm1f(val);
                if (v + j == VT - 1) val = 0.f;
                ((unsigned short*)&stv)[j] = f2bf(val);
            }
            *(ushort4*)(op + v) = stv;
        }
    }
}

// ------- Final conv: barrierless 1-wave 32-row tiles, full unroll, Fin=64, K=1280 -------
__global__ __launch_bounds__(64) void out_mfma(
    const unsigned short* __restrict__ xu, const int* __restrict__ ST,
    const unsigned short* __restrict__ W2T, const float* __restrict__ b2,
    float* __restrict__ out) {
    const int VT = 11794, VP = 11904, TPB = 372, NSTEPS = 40;
    __shared__ __align__(16) unsigned short As[2][32 * 32];
    const int lane = threadIdx.x;
    const int lr = lane & 15;
    const int lko = (lane >> 4) * 8;
    const int bm = blockIdx.x;
    const int b = bm / TPB;
    const int v0 = (bm - b * TPB) * 32;
    const unsigned short* xb = xu + ((size_t)b * VP << 6);

    const int arow = lane >> 1;
    const int h = lane & 1;
    const int v = v0 + arow;
    const int vg = v < VT ? v : VT - 1;
    const int sw0 = arow * 32 + (((2 * h + 0 + ((lane >> 2) & 3)) & 3) * 8);
    const int sw1 = arow * 32 + (((2 * h + 1 + ((lane >> 2) & 3)) & 3) * 8);
    const int fslot = (((lane >> 4) + (lr >> 1)) & 3) * 8;

    int idx[20];
#pragma unroll
    for (int k = 0; k < 20; ++k) idx[k] = ST[(size_t)k * VT + vg];

    f32x4 acc[2];
    acc[0] = {0.f, 0.f, 0.f, 0.f};
    acc[1] = {0.f, 0.f, 0.f, 0.f};

    const unsigned short* wrow = W2T + (size_t)lr * 1288 + lko;
    bf16x8 gA[2][2], bgr[2];

#define OC(AB_, WB_)                                                    \
    {                                                                   \
        bf16x8 af[2];                                                   \
        _Pragma("unroll")                                               \
        for (int mt = 0; mt < 2; ++mt)                                  \
            af[mt] = *(const bf16x8*)&As[AB_][(mt * 16 + lr) * 32 + fslot]; \
        _Pragma("unroll")                                               \
        for (int mt = 0; mt < 2; ++mt)                                  \
            acc[mt] = __builtin_amdgcn_mfma_f32_16x16x32_bf16(          \
                af[mt], bgr[WB_], acc[mt], 0, 0, 0);                    \
    }

    {
        const unsigned short* p = xb + (((size_t)idx[0]) << 6) + h * 16;
        gA[0][0] = *(const bf16x8*)(p);
        gA[0][1] = *(const bf16x8*)(p + 8);
        bgr[0] = *(const bf16x8*)(wrow);
        *(bf16x8*)&As[0][sw0] = gA[0][0];
        *(bf16x8*)&As[0][sw1] = gA[0][1];
    }

#pragma unroll
    for (int ts = 0; ts < NSTEPS - 1; ++ts) {
        const int tn = ts + 1;
        const unsigned short* p =
            xb + (((size_t)idx[tn >> 1]) << 6) + (tn & 1) * 32 + h * 16;
        gA[tn & 1][0] = *(const bf16x8*)(p);
        gA[tn & 1][1] = *(const bf16x8*)(p + 8);
        bgr[tn & 1] = *(const bf16x8*)(wrow + tn * 32);
        OC(ts & 1, ts & 1);
        *(bf16x8*)&As[tn & 1][sw0] = gA[tn & 1][0];
        *(bf16x8*)&As[tn & 1][sw1] = gA[tn & 1][1];
    }
    OC((NSTEPS - 1) & 1, (NSTEPS - 1) & 1);
#undef OC

    if (lr < 3) {
        const float bv = b2[lr];
#pragma unroll
        for (int mt = 0; mt < 2; ++mt) {
#pragma unroll
            for (int j = 0; j < 4; ++j) {
                const int vv = v0 + mt * 16 + (lane >> 4) * 4 + j;
                if (vv < VT) {
                    float val = acc[mt][j] + bv;
                    if (vv == VT - 1) val = 0.f;
                    out[((size_t)b * VT + vv) * 3 + lr] = val;
                }
            }
        }
    }
}

extern "C" void kernel_launch(void* const* d_in, const int* in_sizes, int n_in,
                              void* d_out, int out_size, void* d_ws, size_t ws_size,
                              hipStream_t stream) {
    const float* z   = (const float*)d_in[0];
    const float* U0  = (const float*)d_in[1];
    const float* U1  = (const float*)d_in[2];
    const float* U2  = (const float*)d_in[3];
    const int*   S0  = (const int*)d_in[4];
    const int*   S1  = (const int*)d_in[5];
    const int*   S2  = (const int*)d_in[6];
    const float* Wfc = (const float*)d_in[7];
    const float* bfc = (const float*)d_in[8];
    const float* W0  = (const float*)d_in[9];
    const float* b0  = (const float*)d_in[10];
    const float* W1  = (const float*)d_in[11];
    const float* b1  = (const float*)d_in[12];
    const float* W2  = (const float*)d_in[13];
    const float* b2  = (const float*)d_in[14];
    float* out = (float*)d_out;

    char* ws = (char*)d_ws;
    unsigned short* Ub0 = (unsigned short*)(ws + 0);          // [11904][2976]
    unsigned short* Ub1 = (unsigned short*)(ws + 70852608);   // [3072][768]
    unsigned short* Ub2 = (unsigned short*)(ws + 75571200);   // [768][192]
    unsigned short* x3T = (unsigned short*)(ws + 75866112);   // [2048][192]
    unsigned short* x2u = (unsigned short*)(ws + 76652544);   // [16][768][128]
    unsigned short* x2T = (unsigned short*)(ws + 79798272);   // [2048][768]
    unsigned short* x1u = (unsigned short*)(ws + 82944000);   // [16][3072][128]
    unsigned short* x1T = (unsigned short*)(ws + 95526912);   // [1024][3072]
    unsigned short* x0u = (unsigned short*)(ws + 101818368);  // [16][11904][64]
    unsigned short* W0T = (unsigned short*)(ws + 126197760);  // [128][1536]
    unsigned short* W1T = (unsigned short*)(ws + 126590976);  // [64][1792]
    int* S1T = (int*)(ws + 126820352);                        // [14][2949]
    int* S2T = (int*)(ws + 126985504);                        // [12][738]
    int* S0T = (int*)(ws + 127020928);                        // [20][11794]
    unsigned short* W2T = (unsigned short*)(ws + 127964448);  // [16][1288]

    // 1. fused cvt + FC : 93 fc blocks + 2048 cvt blocks
    cvt_fc<<<dim3(93 + 2048), 256, 0, stream>>>(
        z, Wfc, bfc, x3T,
        U0, U1, U2, (unsigned*)Ub0, (unsigned*)Ub1, (unsigned*)Ub2,
        W0, W1, W2, S0, S1, S2, W0T, W1T, W2T, S0T, S1T, S2T);

    // 2. U2 upsample -> x2u : nsteps=6
    ups_mfma<7, 768><<<dim3(96), 256, 0, stream>>>(Ub2, x3T, x2u, 192, 192, 6, 4, 12);
    // 3. conv0 (K=12,128->128,elu) -> x2T : barrierless, NSTEPS=48
    conv_mfma<768, 48, 12><<<dim3(384, 2), 64, 0, stream>>>(
        x2u, S2T, W0T, b0, x2T, 738, 1536, 128);
    // 4. U1 upsample -> x1u : nsteps=24
    ups_mfma<7, 3072><<<dim3(384), 256, 0, stream>>>(Ub1, x2T, x1u, 768, 768, 24, 4, 48);
    // 5. conv1 (K=14,128->64,elu) -> x1T : barrierless, NSTEPS=56
    conv_mfma<3072, 56, 14><<<dim3(1536, 1), 64, 0, stream>>>(
        x1u, S1T, W1T, b1, x1T, 2949, 1792, 64);
    // 6. U0 upsample -> x0u : nsteps=93
    ups_mfma<6, 11904><<<dim3(744), 256, 0, stream>>>(Ub0, x1T, x0u, 2976, 3072, 93, 3, 93);
    // 7. conv2 (K=20, 64->3) -> d_out : barrierless, NSTEPS=40
    out_mfma<<<dim3(16 * 372), 64, 0, stream>>>(x0u, S0T, W2T, b2, out);
}

// Round 18
// 305.852 us; speedup vs baseline: 1.0367x; 1.0367x over previous
//
#include <hip/hip_runtime.h>
#include <cmath>

// Decoder_spirals R17: exact revert to R15 (best measured, 307.5us).
// R16's fc-into-cvt fusion regressed (+9.6us): host kernel is BW-saturated, so
// guest fc blocks delayed cvt scheduling instead of hiding. Fusion ledger:
// R14 (latency-bound hosts) -41us, R16 (BW-bound host) -10us -> keep separate.
// Structure: cvt_all (BW floor ~40us) -> fc -> [ups/conv ladder at structure
// ceilings] -> out. 8 dispatches.

#define NB 16

typedef __attribute__((ext_vector_type(8))) short bf16x8;
typedef __attribute__((ext_vector_type(4))) float f32x4;

__device__ __forceinline__ unsigned short f2bf(float x) {
    union { float f; unsigned u; } v; v.f = x;
    unsigned r = v.u + 0x7FFFu + ((v.u >> 16) & 1u);
    return (unsigned short)(r >> 16);
}
__device__ __forceinline__ void gload16(const void* src, void* dst) {
    __builtin_amdgcn_global_load_lds(
        (const __attribute__((address_space(1))) unsigned int*)src,
        (__attribute__((address_space(3))) unsigned int*)dst, 16, 0, 0);
}

// ------------- single consolidated converter -------------
__global__ __launch_bounds__(256) void cvt_all(
    const float* __restrict__ U0, const float* __restrict__ U1,
    const float* __restrict__ U2, unsigned* __restrict__ Ub0,
    unsigned* __restrict__ Ub1, unsigned* __restrict__ Ub2,
    const float* __restrict__ W0, const float* __restrict__ W1,
    const float* __restrict__ W2, const int* __restrict__ S0,
    const int* __restrict__ S1, const int* __restrict__ S2,
    unsigned short* __restrict__ W0T, unsigned short* __restrict__ W1T,
    unsigned short* __restrict__ W2T, int* __restrict__ S0T,
    int* __restrict__ S1T, int* __restrict__ S2T) {
    const unsigned nth = gridDim.x * 256u;
    const unsigned tid = blockIdx.x * 256u + threadIdx.x;
    // U0 pairs: [11904][1488]
    for (unsigned p = tid; p < 11904u * 1488u; p += nth) {
        unsigned row = p / 1488u;
        unsigned k = (p - row * 1488u) * 2u;
        float v0 = 0.f, v1 = 0.f;
        if (row < 11794u) {
            const float* s = U0 + (size_t)row * 2949u + k;
            if (k < 2949u) v0 = s[0];
            if (k + 1u < 2949u) v1 = s[1];
        }
        Ub0[p] = (unsigned)f2bf(v0) | ((unsigned)f2bf(v1) << 16);
    }
    // U1 pairs: [3072][384]
    for (unsigned p = tid; p < 3072u * 384u; p += nth) {
        unsigned row = p / 384u;
        unsigned k = (p - row * 384u) * 2u;
        float v0 = 0.f, v1 = 0.f;
        if (row < 2949u) {
            const float* s = U1 + (size_t)row * 738u + k;
            if (k < 738u) v0 = s[0];
            if (k + 1u < 738u) v1 = s[1];
        }
        Ub1[p] = (unsigned)f2bf(v0) | ((unsigned)f2bf(v1) << 16);
    }
    // U2 pairs: [768][96]
    for (unsigned p = tid; p < 768u * 96u; p += nth) {
        unsigned row = p / 96u;
        unsigned k = (p - row * 96u) * 2u;
        float v0 = 0.f, v1 = 0.f;
        if (row < 738u) {
            const float* s = U2 + (size_t)row * 185u + k;
            if (k < 185u) v0 = s[0];
            if (k + 1u < 185u) v1 = s[1];
        }
        Ub2[p] = (unsigned)f2bf(v0) | ((unsigned)f2bf(v1) << 16);
    }
    // weight / spiral transposes
    const unsigned N0 = 128 * 1536, N1 = 64 * 1792, N2 = 16 * 1288;
    const unsigned N3 = 20 * 11794, N4 = 14 * 2949, N5 = 12 * 738;
    const unsigned TOT = N0 + N1 + N2 + N3 + N4 + N5;
    for (unsigned id0 = tid; id0 < TOT; id0 += nth) {
        unsigned id = id0;
        if (id < N0) {
            unsigned n = id / 1536u, k = id - n * 1536u;
            W0T[id] = f2bf(W0[(size_t)k * 128 + n]);
        } else if ((id -= N0) < N1) {
            unsigned n = id / 1792u, k = id - n * 1792u;
            W1T[id] = f2bf(W1[(size_t)k * 64 + n]);
        } else if ((id -= N1) < N2) {
            unsigned n = id / 1288u, k = id - n * 1288u;
            float v = (n < 3u && k < 1280u) ? W2[(size_t)k * 3 + n] : 0.f;
            W2T[id] = f2bf(v);
        } else if ((id -= N2) < N3) {
            unsigned k = id / 11794u, v = id - k * 11794u;
            S0T[id] = S0[(size_t)v * 20 + k];
        } else if ((id -= N3) < N4) {
            unsigned k = id / 2949u, v = id - k * 2949u;
            S1T[id] = S1[(size_t)v * 14 + k];
        } else if ((id -= N4) < N5) {
            unsigned k = id / 738u, v = id - k * 738u;
            S2T[id] = S2[(size_t)v * 12 + k];
        }
    }
}

// -------- FC: z(16,128)@Wfc(128,23680)+bfc -> x3T[b*128+f][192] bf16 (+pad zero) --------
__global__ __launch_bounds__(256) void fc_kernel(const float* __restrict__ z,
                                                 const float* __restrict__ Wfc,
                                                 const float* __restrict__ bfc,
                                                 unsigned short* __restrict__ x3T) {
    const int N = 185 * 128;
    __shared__ float zs[NB * 128];
    int t = threadIdx.x;
    for (int i = t; i < NB * 128; i += 256) zs[i] = z[i];
    __syncthreads();
    int n = blockIdx.x * 256 + t;
    if (n >= N) return;
    float acc[NB];
#pragma unroll
    for (int b = 0; b < NB; ++b) acc[b] = 0.f;
    for (int k = 0; k < 128; ++k) {
        float w = Wfc[k * N + n];
#pragma unroll
        for (int b = 0; b < NB; ++b) acc[b] = fmaf(zs[b * 128 + k], w, acc[b]);
    }
    float bv = bfc[n];
    int f = n & 127, v = n >> 7;
#pragma unroll
    for (int b = 0; b < NB; ++b)
        x3T[(size_t)(b * 128 + f) * 192 + v] = f2bf(acc[b] + bv);
    if (n < 7 * 128) {
        int vp = 185 + (n >> 7);
#pragma unroll
        for (int b = 0; b < NB; ++b)
            x3T[(size_t)(b * 128 + f) * 192 + vp] = 0;
    }
}

// ------------- Upsample: BM=BN=128, wave=64x64; 3-buf, 2-deep, vmcnt(4) -------------
template<int FSH, int VP>
__global__ __launch_bounds__(256) void ups_mfma(
    const unsigned short* __restrict__ Ub, const unsigned short* __restrict__ xT,
    unsigned short* __restrict__ out,
    int WpA, int WpB, int nsteps, int gxsh, int q) {
    const int F = 1 << FSH;
    __shared__ __align__(16) unsigned short As[3][128 * 32];
    __shared__ __align__(16) unsigned short Bs[3][128 * 32];
    const int t = threadIdx.x;
    const int wv = t >> 6, lane = t & 63;
    const int lr = lane & 15;

    const int flat = blockIdx.x;
    const int wg = (flat & 7) * q + (flat >> 3);
    const int m0 = (wg >> gxsh) * 128;
    const int n0 = (wg & ((1 << gxsh) - 1)) * 128;

    const int srow = lane >> 2;
    const int schunk = (((lane & 3) - ((lane >> 3) & 3)) & 3) * 8;
    const int ii0 = wv * 2, ii1 = wv * 2 + 1;
    const unsigned short* asrc0 = Ub + (size_t)(m0 + ii0 * 16 + srow) * WpA + schunk;
    const unsigned short* asrc1 = Ub + (size_t)(m0 + ii1 * 16 + srow) * WpA + schunk;
    const unsigned short* bsrc0 = xT + (size_t)(n0 + ii0 * 16 + srow) * WpB + schunk;
    const unsigned short* bsrc1 = xT + (size_t)(n0 + ii1 * 16 + srow) * WpB + schunk;

    const int fslot = (((lane >> 4) + (lr >> 1)) & 3) * 8;
    const int wrow = (wv >> 1) * 64;
    const int wcol = (wv & 1) * 64;
    const int u0 = wv * 1024;

    f32x4 acc[4][4];
#pragma unroll
    for (int i = 0; i < 4; ++i)
#pragma unroll
        for (int j = 0; j < 4; ++j) acc[i][j] = {0.f, 0.f, 0.f, 0.f};

#define UPS_STAGE(off_, B_)                                             \
    {                                                                   \
        gload16(asrc0 + (off_), &As[B_][u0]);                           \
        gload16(bsrc0 + (off_), &Bs[B_][u0]);                           \
        gload16(asrc1 + (off_), &As[B_][u0 + 512]);                     \
        gload16(bsrc1 + (off_), &Bs[B_][u0 + 512]);                     \
    }
#define UPS_COMPUTE(B_)                                                 \
    {                                                                   \
        bf16x8 af[4], bg[4];                                            \
        _Pragma("unroll")                                               \
        for (int mt = 0; mt < 4; ++mt)                                  \
            af[mt] = *(const bf16x8*)&As[B_][(wrow + mt * 16 + lr) * 32 + fslot]; \
        _Pragma("unroll")                                               \
        for (int nt = 0; nt < 4; ++nt)                                  \
            bg[nt] = *(const bf16x8*)&Bs[B_][(wcol + nt * 16 + lr) * 32 + fslot]; \
        _Pragma("unroll")                                               \
        for (int mt = 0; mt < 4; ++mt)                                  \
            _Pragma("unroll")                                           \
            for (int nt = 0; nt < 4; ++nt)                              \
                acc[mt][nt] = __builtin_amdgcn_mfma_f32_16x16x32_bf16(  \
                    af[mt], bg[nt], acc[mt][nt], 0, 0, 0);              \
    }
#define UPS_WAIT4 asm volatile("s_waitcnt vmcnt(4)" ::: "memory"); __builtin_amdgcn_s_barrier();
#define UPS_WAIT0 asm volatile("s_waitcnt vmcnt(0)" ::: "memory"); __builtin_amdgcn_s_barrier();

    UPS_STAGE(0, 0);
    UPS_STAGE(32, 1);
    UPS_WAIT4;

    const int m = nsteps / 3;
    for (int it = 0; it < m - 1; ++it) {
        UPS_STAGE(64, 2);  UPS_COMPUTE(0); UPS_WAIT4;
        UPS_STAGE(96, 0);  UPS_COMPUTE(1); UPS_WAIT4;
        UPS_STAGE(128, 1); UPS_COMPUTE(2); UPS_WAIT4;
        asrc0 += 96; asrc1 += 96; bsrc0 += 96; bsrc1 += 96;
    }
    UPS_STAGE(64, 2);
    UPS_COMPUTE(0); UPS_WAIT4;
    UPS_COMPUTE(1); UPS_WAIT0;
    UPS_COMPUTE(2);
#undef UPS_STAGE
#undef UPS_COMPUTE
#undef UPS_WAIT4
#undef UPS_WAIT0

#pragma unroll
    for (int mt = 0; mt < 4; ++mt) {
        const int vb = m0 + wrow + mt * 16 + (lane >> 4) * 4;
#pragma unroll
        for (int nt = 0; nt < 4; ++nt) {
            const int col = n0 + wcol + nt * 16 + lr;
            const int b = col >> FSH, f = col & (F - 1);
            unsigned short* op = out + (size_t)b * VP * F + f;
#pragma unroll
            for (int j = 0; j < 4; ++j)
                op[(size_t)(vb + j) * F] = f2bf(acc[mt][nt][j]);
        }
    }
}

// ------- SpiralConv: barrierless 1-wave 32-row tiles, full unroll, Fin=128 -------
template<int VP, int NSTEPS, int KSP>
__global__ __launch_bounds__(64) void conv_mfma(
    const unsigned short* __restrict__ xu, const int* __restrict__ ST,
    const unsigned short* __restrict__ WT, const float* __restrict__ bias,
    unsigned short* __restrict__ outT,
    int VT, int Kdim, int Fout) {
    __shared__ __align__(16) unsigned short As[2][32 * 32];
    __shared__ __align__(16) unsigned short Bs[3][64 * 32];
    const int lane = threadIdx.x;
    const int lr = lane & 15;
    const int m0 = blockIdx.x * 32;
    const int n0 = blockIdx.y * 64;
    const int b = m0 / VP;
    const int v0 = m0 - b * VP;
    const unsigned short* xb = xu + (((size_t)b * VP) << 7);

    const int arow = lane >> 1;
    const int h = lane & 1;
    const int vg = (v0 + arow < VT) ? (v0 + arow) : (VT - 1);
    const int schunk = (((lane & 3) - ((lane >> 3) & 3)) & 3) * 8;
    const int fslot = (((lane >> 4) + (lr >> 1)) & 3) * 8;
    const int sw0 = arow * 32 + (((2 * h + 0 + ((lane >> 2) & 3)) & 3) * 8);
    const int sw1 = arow * 32 + (((2 * h + 1 + ((lane >> 2) & 3)) & 3) * 8);

    int idx[KSP];
#pragma unroll
    for (int k = 0; k < KSP; ++k) idx[k] = ST[(size_t)k * VT + vg];

    f32x4 acc[2][4];
#pragma unroll
    for (int i = 0; i < 2; ++i)
#pragma unroll
        for (int j = 0; j < 4; ++j) acc[i][j] = {0.f, 0.f, 0.f, 0.f};

    bf16x8 gA[2][2];

#define CC(AB_, BB_)                                                    \
    {                                                                   \
        bf16x8 af[2], bg[4];                                            \
        _Pragma("unroll")                                               \
        for (int mt = 0; mt < 2; ++mt)                                  \
            af[mt] = *(const bf16x8*)&As[AB_][(mt * 16 + lr) * 32 + fslot]; \
        _Pragma("unroll")                                               \
        for (int nt = 0; nt < 4; ++nt)                                  \
            bg[nt] = *(const bf16x8*)&Bs[BB_][(nt * 16 + lr) * 32 + fslot]; \
        _Pragma("unroll")                                               \
        for (int mt = 0; mt < 2; ++mt)                                  \
            _Pragma("unroll")                                           \
            for (int nt = 0; nt < 4; ++nt)                              \
                acc[mt][nt] = __builtin_amdgcn_mfma_f32_16x16x32_bf16(  \
                    af[mt], bg[nt], acc[mt][nt], 0, 0, 0);              \
    }

    {
        const unsigned short* p = xb + (((size_t)idx[0]) << 7) + h * 16;
        gA[0][0] = *(const bf16x8*)(p);
        gA[0][1] = *(const bf16x8*)(p + 8);
#pragma unroll
        for (int i = 0; i < 4; ++i) {
            const int n = n0 + i * 16 + (lane >> 2);
            gload16(WT + (size_t)n * Kdim + schunk, &Bs[0][i * 512]);
        }
#pragma unroll
        for (int i = 0; i < 4; ++i) {
            const int n = n0 + i * 16 + (lane >> 2);
            gload16(WT + (size_t)n * Kdim + 32 + schunk, &Bs[1][i * 512]);
        }
        *(bf16x8*)&As[0][sw0] = gA[0][0];
        *(bf16x8*)&As[0][sw1] = gA[0][1];
        asm volatile("s_waitcnt vmcnt(4)" ::: "memory");
    }

#pragma unroll
    for (int ts = 0; ts < NSTEPS - 2; ++ts) {
        const int tn1 = ts + 1, tn2 = ts + 2;
        {
            const unsigned short* p =
                xb + (((size_t)idx[tn1 >> 2]) << 7) + (tn1 & 3) * 32 + h * 16;
            gA[tn1 & 1][0] = *(const bf16x8*)(p);
            gA[tn1 & 1][1] = *(const bf16x8*)(p + 8);
        }
        {
            const int k0 = tn2 * 32;
#pragma unroll
            for (int i = 0; i < 4; ++i) {
                const int n = n0 + i * 16 + (lane >> 2);
                gload16(WT + (size_t)n * Kdim + k0 + schunk, &Bs[tn2 % 3][i * 512]);
            }
        }
        CC(ts & 1, ts % 3);
        asm volatile("s_waitcnt vmcnt(4)" ::: "memory");
        *(bf16x8*)&As[tn1 & 1][sw0] = gA[tn1 & 1][0];
        *(bf16x8*)&As[tn1 & 1][sw1] = gA[tn1 & 1][1];
    }
    {
        const int tn1 = NSTEPS - 1;
        const unsigned short* p =
            xb + (((size_t)idx[tn1 >> 2]) << 7) + (tn1 & 3) * 32 + h * 16;
        gA[tn1 & 1][0] = *(const bf16x8*)(p);
        gA[tn1 & 1][1] = *(const bf16x8*)(p + 8);
        CC((NSTEPS - 2) & 1, (NSTEPS - 2) % 3);
        asm volatile("s_waitcnt vmcnt(0)" ::: "memory");
        *(bf16x8*)&As[tn1 & 1][sw0] = gA[tn1 & 1][0];
        *(bf16x8*)&As[tn1 & 1][sw1] = gA[tn1 & 1][1];
    }
    CC((NSTEPS - 1) & 1, (NSTEPS - 1) % 3);
#undef CC

#pragma unroll
    for (int nt = 0; nt < 4; ++nt) {
        const int n = n0 + nt * 16 + lr;
        const float bv = bias[n];
        unsigned short* op = outT + (size_t)(b * Fout + n) * VP;
#pragma unroll
        for (int mt = 0; mt < 2; ++mt) {
            const int v = v0 + mt * 16 + (lane >> 4) * 4;
            ushort4 stv;
#pragma unroll
            for (int j = 0; j < 4; ++j) {
                float val = acc[mt][nt][j] + bv;
                val = val > 0.f ? val : expm1f(val);
                if (v + j == VT - 1) val = 0.f;
                ((unsigned short*)&stv)[j] = f2bf(val);
            }
            *(ushort4*)(op + v) = stv;
        }
    }
}

// ------- Final conv: barrierless 1-wave 32-row tiles, full unroll, Fin=64, K=1280 -------
__global__ __launch_bounds__(64) void out_mfma(
    const unsigned short* __restrict__ xu, const int* __restrict__ ST,
    const unsigned short* __restrict__ W2T, const float* __restrict__ b2,
    float* __restrict__ out) {
    const int VT = 11794, VP = 11904, TPB = 372, NSTEPS = 40;
    __shared__ __align__(16) unsigned short As[2][32 * 32];
    const int lane = threadIdx.x;
    const int lr = lane & 15;
    const int lko = (lane >> 4) * 8;
    const int bm = blockIdx.x;
    const int b = bm / TPB;
    const int v0 = (bm - b * TPB) * 32;
    const unsigned short* xb = xu + ((size_t)b * VP << 6);

    const int arow = lane >> 1;
    const int h = lane & 1;
    const int v = v0 + arow;
    const int vg = v < VT ? v : VT - 1;
    const int sw0 = arow * 32 + (((2 * h + 0 + ((lane >> 2) & 3)) & 3) * 8);
    const int sw1 = arow * 32 + (((2 * h + 1 + ((lane >> 2) & 3)) & 3) * 8);
    const int fslot = (((lane >> 4) + (lr >> 1)) & 3) * 8;

    int idx[20];
#pragma unroll
    for (int k = 0; k < 20; ++k) idx[k] = ST[(size_t)k * VT + vg];

    f32x4 acc[2];
    acc[0] = {0.f, 0.f, 0.f, 0.f};
    acc[1] = {0.f, 0.f, 0.f, 0.f};

    const unsigned short* wrow = W2T + (size_t)lr * 1288 + lko;
    bf16x8 gA[2][2], bgr[2];

#define OC(AB_, WB_)                                                    \
    {                                                                   \
        bf16x8 af[2];                                                   \
        _Pragma("unroll")                                               \
        for (int mt = 0; mt < 2; ++mt)                                  \
            af[mt] = *(const bf16x8*)&As[AB_][(mt * 16 + lr) * 32 + fslot]; \
        _Pragma("unroll")                                               \
        for (int mt = 0; mt < 2; ++mt)                                  \
            acc[mt] = __builtin_amdgcn_mfma_f32_16x16x32_bf16(          \
                af[mt], bgr[WB_], acc[mt], 0, 0, 0);                    \
    }

    {
        const unsigned short* p = xb + (((size_t)idx[0]) << 6) + h * 16;
        gA[0][0] = *(const bf16x8*)(p);
        gA[0][1] = *(const bf16x8*)(p + 8);
        bgr[0] = *(const bf16x8*)(wrow);
        *(bf16x8*)&As[0][sw0] = gA[0][0];
        *(bf16x8*)&As[0][sw1] = gA[0][1];
    }

#pragma unroll
    for (int ts = 0; ts < NSTEPS - 1; ++ts) {
        const int tn = ts + 1;
        const unsigned short* p =
            xb + (((size_t)idx[tn >> 1]) << 6) + (tn & 1) * 32 + h * 16;
        gA[tn & 1][0] = *(const bf16x8*)(p);
        gA[tn & 1][1] = *(const bf16x8*)(p + 8);
        bgr[tn & 1] = *(const bf16x8*)(wrow + tn * 32);
        OC(ts & 1, ts & 1);
        *(bf16x8*)&As[tn & 1][sw0] = gA[tn & 1][0];
        *(bf16x8*)&As[tn & 1][sw1] = gA[tn & 1][1];
    }
    OC((NSTEPS - 1) & 1, (NSTEPS - 1) & 1);
#undef OC

    if (lr < 3) {
        const float bv = b2[lr];
#pragma unroll
        for (int mt = 0; mt < 2; ++mt) {
#pragma unroll
            for (int j = 0; j < 4; ++j) {
                const int vv = v0 + mt * 16 + (lane >> 4) * 4 + j;
                if (vv < VT) {
                    float val = acc[mt][j] + bv;
                    if (vv == VT - 1) val = 0.f;
                    out[((size_t)b * VT + vv) * 3 + lr] = val;
                }
            }
        }
    }
}

extern "C" void kernel_launch(void* const* d_in, const int* in_sizes, int n_in,
                              void* d_out, int out_size, void* d_ws, size_t ws_size,
                              hipStream_t stream) {
    const float* z   = (const float*)d_in[0];
    const float* U0  = (const float*)d_in[1];
    const float* U1  = (const float*)d_in[2];
    const float* U2  = (const float*)d_in[3];
    const int*   S0  = (const int*)d_in[4];
    const int*   S1  = (const int*)d_in[5];
    const int*   S2  = (const int*)d_in[6];
    const float* Wfc = (const float*)d_in[7];
    const float* bfc = (const float*)d_in[8];
    const float* W0  = (const float*)d_in[9];
    const float* b0  = (const float*)d_in[10];
    const float* W1  = (const float*)d_in[11];
    const float* b1  = (const float*)d_in[12];
    const float* W2  = (const float*)d_in[13];
    const float* b2  = (const float*)d_in[14];
    float* out = (float*)d_out;

    char* ws = (char*)d_ws;
    unsigned short* Ub0 = (unsigned short*)(ws + 0);          // [11904][2976]
    unsigned short* Ub1 = (unsigned short*)(ws + 70852608);   // [3072][768]
    unsigned short* Ub2 = (unsigned short*)(ws + 75571200);   // [768][192]
    unsigned short* x3T = (unsigned short*)(ws + 75866112);   // [2048][192]
    unsigned short* x2u = (unsigned short*)(ws + 76652544);   // [16][768][128]
    unsigned short* x2T = (unsigned short*)(ws + 79798272);   // [2048][768]
    unsigned short* x1u = (unsigned short*)(ws + 82944000);   // [16][3072][128]
    unsigned short* x1T = (unsigned short*)(ws + 95526912);   // [1024][3072]
    unsigned short* x0u = (unsigned short*)(ws + 101818368);  // [16][11904][64]
    unsigned short* W0T = (unsigned short*)(ws + 126197760);  // [128][1536]
    unsigned short* W1T = (unsigned short*)(ws + 126590976);  // [64][1792]
    int* S1T = (int*)(ws + 126820352);                        // [14][2949]
    int* S2T = (int*)(ws + 126985504);                        // [12][738]
    int* S0T = (int*)(ws + 127020928);                        // [20][11794]
    unsigned short* W2T = (unsigned short*)(ws + 127964448);  // [16][1288]

    cvt_all<<<dim3(2048), 256, 0, stream>>>(
        U0, U1, U2, (unsigned*)Ub0, (unsigned*)Ub1, (unsigned*)Ub2,
        W0, W1, W2, S0, S1, S2, W0T, W1T, W2T, S0T, S1T, S2T);

    // 1. FC -> x3T (incl. pad-zero)
    fc_kernel<<<dim3((185 * 128 + 255) / 256), 256, 0, stream>>>(z, Wfc, bfc, x3T);
    // 2. U2 upsample -> x2u : nsteps=6
    ups_mfma<7, 768><<<dim3(96), 256, 0, stream>>>(Ub2, x3T, x2u, 192, 192, 6, 4, 12);
    // 3. conv0 (K=12,128->128,elu) -> x2T : barrierless, NSTEPS=48
    conv_mfma<768, 48, 12><<<dim3(384, 2), 64, 0, stream>>>(
        x2u, S2T, W0T, b0, x2T, 738, 1536, 128);
    // 4. U1 upsample -> x1u : nsteps=24
    ups_mfma<7, 3072><<<dim3(384), 256, 0, stream>>>(Ub1, x2T, x1u, 768, 768, 24, 4, 48);
    // 5. conv1 (K=14,128->64,elu) -> x1T : barrierless, NSTEPS=56
    conv_mfma<3072, 56, 14><<<dim3(1536, 1), 64, 0, stream>>>(
        x1u, S1T, W1T, b1, x1T, 2949, 1792, 64);
    // 6. U0 upsample -> x0u : nsteps=93
    ups_mfma<6, 11904><<<dim3(744), 256, 0, stream>>>(Ub0, x1T, x0u, 2976, 3072, 93, 3, 93);
    // 7. conv2 (K=20, 64->3) -> d_out : barrierless, NSTEPS=40
    out_mfma<<<dim3(16 * 372), 64, 0, stream>>>(x0u, S0T, W2T, b2, out);
}